// Round 9
// baseline (261.777 us; speedup 1.0000x reference)
//
#include <hip/hip_runtime.h>

typedef __attribute__((__ext_vector_type__(8))) _Float16 f16x8;
typedef __attribute__((__ext_vector_type__(4))) float f32x4;
typedef __attribute__((__ext_vector_type__(4))) int i32x4;

#define HW 56
#define HW2 3136
#define CIN 128
#define COUT 256
#define NB 32
#define NPIX 100352  // 32*3136
#define PH 58        // padded spatial dim (1-px halo)

static __device__ __forceinline__ unsigned short f2h(float f) {
  _Float16 h = (_Float16)f;
  return __builtin_bit_cast(unsigned short, h);
}

// ---- prep_x: x NCHW f32 -> x_pad [32][58][58][128] f16 + channel-sum xs;
//      blocks >= NB*HW zero the 1-px halo ----
__global__ __launch_bounds__(256) void prep_x(const float* __restrict__ x,
                                              unsigned short* __restrict__ xp,
                                              float* __restrict__ xs) {
  if (blockIdx.x >= NB * HW) {  // halo-zero blocks
    int t = (blockIdx.x - NB * HW) * 256 + threadIdx.x;  // < 32*228*16
    int ck = t & 15;
    int pi = t >> 4;
    int b = pi / 228, r = pi - b * 228;
    int h, w;
    if (r < 58) { h = 0; w = r; }
    else if (r < 116) { h = 57; w = r - 58; }
    else { int q = r - 116; h = 1 + (q >> 1); w = (q & 1) * 57; }
    size_t off = (((size_t)(b * PH + h) * PH + w) << 8) + (ck << 4);
    *reinterpret_cast<i32x4*>((char*)xp + off) = (i32x4){0, 0, 0, 0};
    return;
  }
  __shared__ float tile[CIN * 57];  // [c][w], stride 57 kills bank conflicts
  const int bh = blockIdx.x;        // b*56 + h
  const float* src = x + (size_t)(bh / HW) * CIN * HW2 + (size_t)(bh % HW) * HW;
  for (int idx = threadIdx.x; idx < CIN * HW; idx += 256) {
    int c = idx / HW, w = idx - c * HW;
    tile[c * 57 + w] = src[(size_t)c * HW2 + w];
  }
  __syncthreads();
  unsigned short* dst =
      xp + (((size_t)(bh / HW) * PH + (bh % HW) + 1) * PH + 1) * CIN;
  for (int idx = threadIdx.x; idx < HW * (CIN / 2); idx += 256) {
    int w = idx >> 6;         // pixel within row
    int c = (idx & 63) << 1;  // channel pair
    unsigned lo = f2h(tile[c * 57 + w]);
    unsigned hi = f2h(tile[(c + 1) * 57 + w]);
    *reinterpret_cast<unsigned*>(&dst[w * CIN + c]) = lo | (hi << 16);
  }
  if (threadIdx.x < HW) {
    float s = 0.f;
    for (int c = 0; c < CIN; ++c) s += tile[c * 57 + threadIdx.x];
    xs[(size_t)bh * HW + threadIdx.x] = s;
  }
}

// ---- prep_w: core [COUT][CIN][3][3] f32 -> w_t [COUT][9][CIN] f16 ----
__global__ __launch_bounds__(256) void prep_w(const float* __restrict__ core,
                                              unsigned short* __restrict__ w_t) {
  int i = blockIdx.x * 256 + threadIdx.x;  // < 256*9*128
  int c = i & 127;
  int p = (i >> 7) % 9;
  int m = i / (9 * 128);
  w_t[i] = f2h(core[(size_t)(m * CIN + c) * 9 + p]);
}

// ---- periphery stencil on xs ----
__global__ __launch_bounds__(256) void periph_k(const float* __restrict__ xs,
                                                const float* __restrict__ per,
                                                float* __restrict__ po) {
  int n = blockIdx.x * 256 + threadIdx.x;
  int b = n / HW2, r = n - b * HW2;
  int ho = r / HW, wo = r - ho * HW;
  const float* xb = xs + (size_t)b * HW2;
  const int pdy[16] = {0,0,0,0,0,1,1,2,2,3,3,4,4,4,4,4};
  const int pdx[16] = {0,1,2,3,4,0,4,0,4,0,4,0,1,2,3,4};
  float acc = 0.f;
#pragma unroll
  for (int t = 0; t < 16; ++t) {
    int h = ho + pdy[t] - 2, w = wo + pdx[t] - 2;
    if ((unsigned)h < HW && (unsigned)w < HW) acc += per[t] * xb[h * HW + w];
  }
  po[n] = acc;
}

// ---- all-register direct implicit GEMM: NO LDS, NO barriers ----
// Block = 4 independent waves; wave tile 64 couts x 64 px; block = 256 couts
// x 64 px. MFMA fragments loaded DIRECTLY from global (w_t / x_pad) as
// global_load_dwordx4: row=(lane&15), 16B k-chunk=(lane>>4) -> 16 rows x 64B
// = 16 cache lines per load (theoretical minimum). A (0.6MB) and per-XCD x
// window (~3.4MB) are L2-resident; wave redundancy absorbed by L1/L2.
// Manual 2x-unrolled frag double-buffer (named pa/pb | qa/qb, rule-20-safe);
// compiler inserts counted vmcnt (8 newer outstanding when a buffer is
// consumed). 36 K-tiles (9 taps x 4 c-quarters, BK=32). 12 waves/CU.
__global__ __launch_bounds__(256, 3) void gemm_k(const unsigned short* __restrict__ xp,
                                                 const unsigned short* __restrict__ w_t,
                                                 const float* __restrict__ po,
                                                 const float* __restrict__ thresh,
                                                 const float* __restrict__ scale,
                                                 float* __restrict__ out) {
  const int tid = threadIdx.x;
  const int lane = tid & 63;
  const int wm = tid >> 6;  // 0..3 (cout quadrant)

  // XCD-chunked bijective swizzle: nwg=1568=8*196
  const int bid = blockIdx.x;
  const int n0 = ((bid & 7) * 196 + (bid >> 3)) << 6;

  const char* xpc = (const char*)xp;
  const char* wtc = (const char*)w_t;

  // per-lane fragment base offsets (center tap, c-quarter 0)
  int aOff[4], bOff[4];
#pragma unroll
  for (int i = 0; i < 4; ++i)
    aOff[i] = (wm * 64 + i * 16 + (lane & 15)) * 2304 + ((lane >> 4) << 4);
#pragma unroll
  for (int j = 0; j < 4; ++j) {
    int n = n0 + j * 16 + (lane & 15);
    int b = n / HW2, rr = n - b * HW2;
    int h = rr / HW, w = rr - h * HW;
    bOff[j] = ((b * PH + h + 1) * PH + (w + 1)) * 256 + ((lane >> 4) << 4);
  }

  auto toffA = [](int t) { return ((t >> 2) << 8) + ((t & 3) << 6); };
  auto toffB = [](int t) {
    int p = t >> 2;
    int dy = p / 3 - 1, dx = p - (p / 3) * 3 - 1;
    return ((dy * PH + dx) << 8) + ((t & 3) << 6);
  };

#define LOADT(A, B, t)                                                    \
  {                                                                       \
    const int ta_ = toffA(t), tb_ = toffB(t);                             \
    _Pragma("unroll") for (int i_ = 0; i_ < 4; ++i_)                      \
        A[i_] = *reinterpret_cast<const f16x8*>(wtc + aOff[i_] + ta_);    \
    _Pragma("unroll") for (int j_ = 0; j_ < 4; ++j_)                      \
        B[j_] = *reinterpret_cast<const f16x8*>(xpc + bOff[j_] + tb_);    \
  }

  f32x4 acc[4][4] = {};
  f16x8 pa[4], pb[4], qa[4], qb[4];

  LOADT(pa, pb, 0)
  for (int tt = 0; tt < 18; ++tt) {
    const int t = 2 * tt;
    LOADT(qa, qb, t + 1)
    __builtin_amdgcn_s_setprio(1);
#pragma unroll
    for (int i = 0; i < 4; ++i)
#pragma unroll
      for (int j = 0; j < 4; ++j)
        acc[i][j] = __builtin_amdgcn_mfma_f32_16x16x32_f16(pa[i], pb[j], acc[i][j], 0, 0, 0);
    __builtin_amdgcn_s_setprio(0);
    if (t + 2 < 36) LOADT(pa, pb, t + 2)
    __builtin_amdgcn_s_setprio(1);
#pragma unroll
    for (int i = 0; i < 4; ++i)
#pragma unroll
      for (int j = 0; j < 4; ++j)
        acc[i][j] = __builtin_amdgcn_mfma_f32_16x16x32_f16(qa[i], qb[j], acc[i][j], 0, 0, 0);
    __builtin_amdgcn_s_setprio(0);
  }
#undef LOADT

  const float sc = scale[0];
#pragma unroll
  for (int j = 0; j < 4; ++j) {
    int n = n0 + j * 16 + (lane & 15);
    int b = n / HW2;
    int r = n - b * HW2;  // ho*56+wo
    float pv = po[n];
    float* op = out + (size_t)b * (COUT * HW2) + r;
#pragma unroll
    for (int i = 0; i < 4; ++i) {
      int cl = wm * 64 + i * 16 + ((lane >> 4) << 2);
      f32x4 th = *reinterpret_cast<const f32x4*>(&thresh[cl]);
#pragma unroll
      for (int q = 0; q < 4; ++q) {
        float cv = acc[i][j][q];
        float g = 1.f / (1.f + __expf(-sc * (cv - th[q])));
        op[(size_t)(cl + q) * HW2] = cv + g * pv;
      }
    }
  }
}

extern "C" void kernel_launch(void* const* d_in, const int* in_sizes, int n_in,
                              void* d_out, int out_size, void* d_ws, size_t ws_size,
                              hipStream_t stream) {
  (void)in_sizes; (void)n_in; (void)out_size; (void)ws_size;
  const float* x      = (const float*)d_in[0];
  const float* core   = (const float*)d_in[1];
  const float* per    = (const float*)d_in[2];
  const float* thresh = (const float*)d_in[3];
  const float* scale  = (const float*)d_in[4];
  float* out = (float*)d_out;

  char* ws = (char*)d_ws;
  unsigned short* xp  = (unsigned short*)ws;                  // 32*58*58*128*2 = 27,557,888 B
  unsigned short* w_t = (unsigned short*)(ws + 27557888);     // 589,824 B
  float* xs           = (float*)(ws + 28147712);              // 401,408 B
  float* po           = (float*)(ws + 28549120);              // 401,408 B

  prep_x<<<NB * HW + 456, 256, 0, stream>>>(x, xp, xs);  // +456 halo blocks
  prep_w<<<(COUT * 9 * CIN) / 256, 256, 0, stream>>>(core, w_t);
  periph_k<<<NPIX / 256, 256, 0, stream>>>(xs, per, po);
  gemm_k<<<NPIX / 64, 256, 0, stream>>>(xp, w_t, po, thresh, scale, out);
}

// Round 10
// 117.606 us; speedup vs baseline: 2.2259x; 2.2259x over previous
//
#include <hip/hip_runtime.h>

typedef __attribute__((__ext_vector_type__(8))) _Float16 f16x8;
typedef __attribute__((__ext_vector_type__(4))) float f32x4;
typedef __attribute__((__ext_vector_type__(4))) int i32x4;

#define HW 56
#define HW2 3136
#define CIN 128
#define COUT 256
#define NB 32
#define NPIX 100352  // 32*3136
#define PH 58        // padded spatial dim (1-px halo)

static __device__ __forceinline__ unsigned short f2h(float f) {
  _Float16 h = (_Float16)f;
  return __builtin_bit_cast(unsigned short, h);
}

#define GLD_LDS16(g, l)                                          \
  __builtin_amdgcn_global_load_lds(                              \
      (const __attribute__((address_space(1))) void*)(g),        \
      (__attribute__((address_space(3))) void*)(l), 16, 0, 0)

// ---- prep_x: x NCHW f32 -> x_pad [32][58][58][128] f16 + channel-sum xs;
//      blocks >= NB*HW zero the 1-px halo ----
__global__ __launch_bounds__(256) void prep_x(const float* __restrict__ x,
                                              unsigned short* __restrict__ xp,
                                              float* __restrict__ xs) {
  if (blockIdx.x >= NB * HW) {  // halo-zero blocks
    int t = (blockIdx.x - NB * HW) * 256 + threadIdx.x;  // < 32*228*16
    int ck = t & 15;
    int pi = t >> 4;
    int b = pi / 228, r = pi - b * 228;
    int h, w;
    if (r < 58) { h = 0; w = r; }
    else if (r < 116) { h = 57; w = r - 58; }
    else { int q = r - 116; h = 1 + (q >> 1); w = (q & 1) * 57; }
    size_t off = (((size_t)(b * PH + h) * PH + w) << 8) + (ck << 4);
    *reinterpret_cast<i32x4*>((char*)xp + off) = (i32x4){0, 0, 0, 0};
    return;
  }
  __shared__ float tile[CIN * 57];  // [c][w], stride 57 kills bank conflicts
  const int bh = blockIdx.x;        // b*56 + h
  const float* src = x + (size_t)(bh / HW) * CIN * HW2 + (size_t)(bh % HW) * HW;
  for (int idx = threadIdx.x; idx < CIN * HW; idx += 256) {
    int c = idx / HW, w = idx - c * HW;
    tile[c * 57 + w] = src[(size_t)c * HW2 + w];
  }
  __syncthreads();
  unsigned short* dst =
      xp + (((size_t)(bh / HW) * PH + (bh % HW) + 1) * PH + 1) * CIN;
  for (int idx = threadIdx.x; idx < HW * (CIN / 2); idx += 256) {
    int w = idx >> 6;         // pixel within row
    int c = (idx & 63) << 1;  // channel pair
    unsigned lo = f2h(tile[c * 57 + w]);
    unsigned hi = f2h(tile[(c + 1) * 57 + w]);
    *reinterpret_cast<unsigned*>(&dst[w * CIN + c]) = lo | (hi << 16);
  }
  if (threadIdx.x < HW) {
    float s = 0.f;
    for (int c = 0; c < CIN; ++c) s += tile[c * 57 + threadIdx.x];
    xs[(size_t)bh * HW + threadIdx.x] = s;
  }
}

// ---- prep_w: core [COUT][CIN][3][3] f32 -> w_t [COUT][9][CIN] f16 ----
__global__ __launch_bounds__(256) void prep_w(const float* __restrict__ core,
                                              unsigned short* __restrict__ w_t) {
  int i = blockIdx.x * 256 + threadIdx.x;  // < 256*9*128
  int c = i & 127;
  int p = (i >> 7) % 9;
  int m = i / (9 * 128);
  w_t[i] = f2h(core[(size_t)(m * CIN + c) * 9 + p]);
}

// ---- periphery stencil on xs ----
__global__ __launch_bounds__(256) void periph_k(const float* __restrict__ xs,
                                                const float* __restrict__ per,
                                                float* __restrict__ po) {
  int n = blockIdx.x * 256 + threadIdx.x;
  int b = n / HW2, r = n - b * HW2;
  int ho = r / HW, wo = r - ho * HW;
  const float* xb = xs + (size_t)b * HW2;
  const int pdy[16] = {0,0,0,0,0,1,1,2,2,3,3,4,4,4,4,4};
  const int pdx[16] = {0,1,2,3,4,0,4,0,4,0,4,0,1,2,3,4};
  float acc = 0.f;
#pragma unroll
  for (int t = 0; t < 16; ++t) {
    int h = ho + pdy[t] - 2, w = wo + pdx[t] - 2;
    if ((unsigned)h < HW && (unsigned)w < HW) acc += per[t] * xb[h * HW + w];
  }
  po[n] = acc;
}

// ---- implicit-GEMM conv, BM=128 BN=128 BK=32, small blocks for max
// cross-block TLP: 4 waves (2M x 2N), wave tile 64x64 (acc 64 regs),
// LDS dbuf 2 x 16KB = 32KB -> 5 blocks/CU co-residency (20 waves/CU).
// The only lever that has paid this session is independent-blocks/CU
// (R6: 1->2 = +13%); this pushes 2->~5. Counted vmcnt(4) depth-1
// prefetch; raw barrier pair per K-tile; 2-way-free LDS swizzle;
// XCD-chunked swizzle with cout-pairs adjacent (shared x window in L2).
// 36 K-tiles (9 taps x 4 c-quarters).
__global__ __launch_bounds__(256, 4) void gemm_k(const unsigned short* __restrict__ xp,
                                                 const unsigned short* __restrict__ w_t,
                                                 const float* __restrict__ po,
                                                 const float* __restrict__ thresh,
                                                 const float* __restrict__ scale,
                                                 float* __restrict__ out) {
  __shared__ __align__(16) char sMem[2 * 16384];  // [A 8KB | B 8KB] x 2

  const int tid = threadIdx.x;
  const int lane = tid & 63;
  const int wid = tid >> 6;  // 0..3
  const int wm = wid >> 1;   // 0..1 (cout half of 128)
  const int wn = wid & 1;    // 0..1 (pixel half of 128)

  // XCD-chunked bijective swizzle: nwg=1568=8*196; cout-pair adjacent
  const int bid = blockIdx.x;
  const int sb = (bid & 7) * 196 + (bid >> 3);
  const int m0 = (sb & 1) << 7;   // 0 or 128
  const int n0 = (sb >> 1) << 7;  // pixel tile base

  // ---- staging addresses (linear LDS dest + inverse-swizzled global src) ----
  const int l4 = lane >> 2;  // row within 16-row chunk
  const int ls = lane & 3;   // 16B slot within 64B row
  const int sw = (ls ^ ((l4 >> 1) & 3)) << 4;  // chunk bases %16==0 -> row swz == l4 swz
  const char* xpc = (const char*)xp;
  const char* wtc = (const char*)w_t;
  int aSrc[2], bSrc[2];
#pragma unroll
  for (int k = 0; k < 2; ++k) {
    int r = wid * 32 + k * 16 + l4;            // row 0..127
    aSrc[k] = (m0 + r) * 2304 + sw;            // 2304 = 9*128*2B
    int n = n0 + r;
    int b = n / HW2, rr = n - b * HW2;
    int h = rr / HW, w = rr - h * HW;
    bSrc[k] = ((b * PH + h + 1) * PH + (w + 1)) * 256 + sw;
  }
  const int aDst = wid * 2048;         // wave-uniform
  const int bDst = 8192 + wid * 2048;

  // ---- fragment read offsets (swizzled) ----
  int aro[4], bro[4];
#pragma unroll
  for (int i = 0; i < 4; ++i) {
    int rowA = wm * 64 + i * 16 + (lane & 15);
    aro[i] = rowA * 64 + ((((lane >> 4) ^ (rowA >> 1)) & 3) << 4);
  }
#pragma unroll
  for (int j = 0; j < 4; ++j) {
    int rowB = wn * 64 + j * 16 + (lane & 15);
    bro[j] = 8192 + rowB * 64 + ((((lane >> 4) ^ (rowB >> 1)) & 3) << 4);
  }

  auto STAGE = [&](int buf, int t) {
    const int p = t >> 2;               // tap 0..8
    const int cq = t & 3;               // channel quarter
    const int dy = p / 3 - 1, dx = p - (p / 3) * 3 - 1;
    const int offA = (p << 8) + (cq << 6);
    const int offB = ((dy * PH + dx) << 8) + (cq << 6);
    char* base = sMem + buf * 16384;
    GLD_LDS16(wtc + aSrc[0] + offA, base + aDst);
    GLD_LDS16(wtc + aSrc[1] + offA, base + aDst + 1024);
    GLD_LDS16(xpc + bSrc[0] + offB, base + bDst);
    GLD_LDS16(xpc + bSrc[1] + offB, base + bDst + 1024);
  };

  f32x4 acc[4][4] = {};

  STAGE(0, 0);
  __syncthreads();  // drains stage(0)

  for (int t = 0; t < 36; ++t) {
    const char* base = sMem + (t & 1) * 16384;
    __builtin_amdgcn_s_barrier();  // B1: reads of buf^1 (iter t-1) complete
    if (t < 35) {
      STAGE((t + 1) & 1, t + 1);
      asm volatile("s_waitcnt vmcnt(4)" ::: "memory");  // stage(t) landed
    } else {
      asm volatile("s_waitcnt vmcnt(0)" ::: "memory");
    }
    __builtin_amdgcn_s_barrier();  // B2: everyone's stage(t) landed

    f16x8 bfr[4];
#pragma unroll
    for (int j = 0; j < 4; ++j)
      bfr[j] = *reinterpret_cast<const f16x8*>(base + bro[j]);
#pragma unroll
    for (int i = 0; i < 4; ++i) {
      f16x8 af = *reinterpret_cast<const f16x8*>(base + aro[i]);
      __builtin_amdgcn_s_setprio(1);
#pragma unroll
      for (int j = 0; j < 4; ++j)
        acc[i][j] = __builtin_amdgcn_mfma_f32_16x16x32_f16(af, bfr[j], acc[i][j], 0, 0, 0);
      __builtin_amdgcn_s_setprio(0);
    }
  }

  const float sc = scale[0];
#pragma unroll
  for (int j = 0; j < 4; ++j) {
    int n = n0 + wn * 64 + j * 16 + (lane & 15);
    int b = n / HW2;
    int r = n - b * HW2;  // ho*56+wo
    float pv = po[n];
    float* op = out + (size_t)b * (COUT * HW2) + r;
#pragma unroll
    for (int i = 0; i < 4; ++i) {
      int cl = m0 + wm * 64 + i * 16 + ((lane >> 4) << 2);
      f32x4 th = *reinterpret_cast<const f32x4*>(&thresh[cl]);
#pragma unroll
      for (int q = 0; q < 4; ++q) {
        float cv = acc[i][j][q];
        float g = 1.f / (1.f + __expf(-sc * (cv - th[q])));
        op[(size_t)(cl + q) * HW2] = cv + g * pv;
      }
    }
  }
}

extern "C" void kernel_launch(void* const* d_in, const int* in_sizes, int n_in,
                              void* d_out, int out_size, void* d_ws, size_t ws_size,
                              hipStream_t stream) {
  (void)in_sizes; (void)n_in; (void)out_size; (void)ws_size;
  const float* x      = (const float*)d_in[0];
  const float* core   = (const float*)d_in[1];
  const float* per    = (const float*)d_in[2];
  const float* thresh = (const float*)d_in[3];
  const float* scale  = (const float*)d_in[4];
  float* out = (float*)d_out;

  char* ws = (char*)d_ws;
  unsigned short* xp  = (unsigned short*)ws;                  // 32*58*58*128*2 = 27,557,888 B
  unsigned short* w_t = (unsigned short*)(ws + 27557888);     // 589,824 B
  float* xs           = (float*)(ws + 28147712);              // 401,408 B
  float* po           = (float*)(ws + 28549120);              // 401,408 B

  prep_x<<<NB * HW + 456, 256, 0, stream>>>(x, xp, xs);  // +456 halo blocks
  prep_w<<<(COUT * 9 * CIN) / 256, 256, 0, stream>>>(core, w_t);
  periph_k<<<NPIX / 256, 256, 0, stream>>>(xs, per, po);
  gemm_k<<<2 * (NPIX / 128), 256, 0, stream>>>(xp, w_t, po, thresh, scale, out);
}

// Round 11
// 112.954 us; speedup vs baseline: 2.3176x; 1.0412x over previous
//
#include <hip/hip_runtime.h>

typedef __attribute__((__ext_vector_type__(8))) _Float16 f16x8;
typedef __attribute__((__ext_vector_type__(4))) float f32x4;
typedef __attribute__((__ext_vector_type__(4))) int i32x4;

#define HW 56
#define HW2 3136
#define CIN 128
#define COUT 256
#define NB 32
#define NPIX 100352  // 32*3136
#define PH 58        // padded spatial dim (1-px halo)

static __device__ __forceinline__ unsigned short f2h(float f) {
  _Float16 h = (_Float16)f;
  return __builtin_bit_cast(unsigned short, h);
}

#define GLD_LDS16(g, l)                                          \
  __builtin_amdgcn_global_load_lds(                              \
      (const __attribute__((address_space(1))) void*)(g),        \
      (__attribute__((address_space(3))) void*)(l), 16, 0, 0)

// ---- prep_x: x NCHW f32 -> x_pad [32][58][58][128] f16 + channel-sum xs;
//      blocks >= NB*HW zero the 1-px halo ----
__global__ __launch_bounds__(256) void prep_x(const float* __restrict__ x,
                                              unsigned short* __restrict__ xp,
                                              float* __restrict__ xs) {
  if (blockIdx.x >= NB * HW) {  // halo-zero blocks
    int t = (blockIdx.x - NB * HW) * 256 + threadIdx.x;  // < 32*228*16
    int ck = t & 15;
    int pi = t >> 4;
    int b = pi / 228, r = pi - b * 228;
    int h, w;
    if (r < 58) { h = 0; w = r; }
    else if (r < 116) { h = 57; w = r - 58; }
    else { int q = r - 116; h = 1 + (q >> 1); w = (q & 1) * 57; }
    size_t off = (((size_t)(b * PH + h) * PH + w) << 8) + (ck << 4);
    *reinterpret_cast<i32x4*>((char*)xp + off) = (i32x4){0, 0, 0, 0};
    return;
  }
  __shared__ float tile[CIN * 57];  // [c][w], stride 57 kills bank conflicts
  const int bh = blockIdx.x;        // b*56 + h
  const float* src = x + (size_t)(bh / HW) * CIN * HW2 + (size_t)(bh % HW) * HW;
  for (int idx = threadIdx.x; idx < CIN * HW; idx += 256) {
    int c = idx / HW, w = idx - c * HW;
    tile[c * 57 + w] = src[(size_t)c * HW2 + w];
  }
  __syncthreads();
  unsigned short* dst =
      xp + (((size_t)(bh / HW) * PH + (bh % HW) + 1) * PH + 1) * CIN;
  for (int idx = threadIdx.x; idx < HW * (CIN / 2); idx += 256) {
    int w = idx >> 6;         // pixel within row
    int c = (idx & 63) << 1;  // channel pair
    unsigned lo = f2h(tile[c * 57 + w]);
    unsigned hi = f2h(tile[(c + 1) * 57 + w]);
    *reinterpret_cast<unsigned*>(&dst[w * CIN + c]) = lo | (hi << 16);
  }
  if (threadIdx.x < HW) {
    float s = 0.f;
    for (int c = 0; c < CIN; ++c) s += tile[c * 57 + threadIdx.x];
    xs[(size_t)bh * HW + threadIdx.x] = s;
  }
}

// ---- prep_w: core [COUT][CIN][3][3] f32 -> w_t [COUT][9][CIN] f16 ----
__global__ __launch_bounds__(256) void prep_w(const float* __restrict__ core,
                                              unsigned short* __restrict__ w_t) {
  int i = blockIdx.x * 256 + threadIdx.x;  // < 256*9*128
  int c = i & 127;
  int p = (i >> 7) % 9;
  int m = i / (9 * 128);
  w_t[i] = f2h(core[(size_t)(m * CIN + c) * 9 + p]);
}

// ---- periphery stencil on xs ----
__global__ __launch_bounds__(256) void periph_k(const float* __restrict__ xs,
                                                const float* __restrict__ per,
                                                float* __restrict__ po) {
  int n = blockIdx.x * 256 + threadIdx.x;
  int b = n / HW2, r = n - b * HW2;
  int ho = r / HW, wo = r - ho * HW;
  const float* xb = xs + (size_t)b * HW2;
  const int pdy[16] = {0,0,0,0,0,1,1,2,2,3,3,4,4,4,4,4};
  const int pdx[16] = {0,1,2,3,4,0,4,0,4,0,4,0,1,2,3,4};
  float acc = 0.f;
#pragma unroll
  for (int t = 0; t < 16; ++t) {
    int h = ho + pdy[t] - 2, w = wo + pdx[t] - 2;
    if ((unsigned)h < HW && (unsigned)w < HW) acc += per[t] * xb[h * HW + w];
  }
  po[n] = acc;
}

// ---- implicit-GEMM conv, BM=128 BN=128 BK=64: halved sync-event rate ----
// 4 waves (2M x 2N), wave tile 64x64. 18 K-tiles (9 taps x 2 c-halves);
// per tile each wave: 16 ds_read_b128 + 32 MFMA between ONE barrier pair
// (36 barriers/block vs R10's 72 — R10 showed occupancy saturation at
// 92us with 40% sync stall; this doubles work per sync event instead).
// LDS dbuf 2 x [A 16KB | B 16KB] = 64KB -> 2 blocks/CU. 128B rows, full
// 8-slot XOR involution slot^=(row&7) (2-way free, 0 conflicts measured).
// Counted vmcnt(8) (8 glds/wave/stage); raw barrier pair; XCD swizzle
// with cout-pairs adjacent (shared x window in L2).
__global__ __launch_bounds__(256, 2) void gemm_k(const unsigned short* __restrict__ xp,
                                                 const unsigned short* __restrict__ w_t,
                                                 const float* __restrict__ po,
                                                 const float* __restrict__ thresh,
                                                 const float* __restrict__ scale,
                                                 float* __restrict__ out) {
  __shared__ __align__(16) char sMem[2 * 32768];  // [A 16KB | B 16KB] x 2

  const int tid = threadIdx.x;
  const int lane = tid & 63;
  const int wid = tid >> 6;  // 0..3
  const int wm = wid >> 1;   // 0..1 (cout half of 128)
  const int wn = wid & 1;    // 0..1 (pixel half of 128)

  // XCD-chunked bijective swizzle: nwg=1568=8*196; cout-pair adjacent
  const int bid = blockIdx.x;
  const int sb = (bid & 7) * 196 + (bid >> 3);
  const int m0 = (sb & 1) << 7;   // 0 or 128
  const int n0 = (sb >> 1) << 7;  // pixel tile base

  // ---- staging addresses (linear LDS dest + inverse-swizzled global src) ----
  const int l8 = lane >> 3;  // row within 8-row chunk (== row&7)
  const int ls = lane & 7;   // 16B slot within 128B row
  const int sw = (ls ^ l8) << 4;  // pre-swizzled slot (chunk bases are 8-row aligned)
  const char* xpc = (const char*)xp;
  const char* wtc = (const char*)w_t;
  // A: wave wid stages rows wid*32 .. wid*32+31 as 4 chunks of 8 rows
  const int aSrc0 = (m0 + wid * 32 + l8) * 2304 + sw;  // +c*18432 per chunk (8*2304)
  // B: wave wid stages pixel rows wid*32+c*8+l8
  int bSrc[4];
#pragma unroll
  for (int c = 0; c < 4; ++c) {
    int n = n0 + wid * 32 + c * 8 + l8;
    int b = n / HW2, rr = n - b * HW2;
    int h = rr / HW, w = rr - h * HW;
    bSrc[c] = ((b * PH + h + 1) * PH + (w + 1)) * 256 + sw;
  }
  const int aDst = wid * 4096;          // 4 chunks x 1KB, wave-uniform
  const int bDst = 16384 + wid * 4096;

  // ---- fragment read offsets (swizzled) ----
  int aro[4][2], bro[4][2];
#pragma unroll
  for (int i = 0; i < 4; ++i)
#pragma unroll
    for (int ko = 0; ko < 2; ++ko) {
      int rowA = wm * 64 + i * 16 + (lane & 15);
      int rowB = wn * 64 + i * 16 + (lane & 15);
      int boc = ko * 64 + ((lane >> 4) << 4);
      aro[i][ko] = rowA * 128 + (boc ^ ((rowA & 7) << 4));
      bro[i][ko] = 16384 + rowB * 128 + (boc ^ ((rowB & 7) << 4));
    }

  auto STAGE = [&](int buf, int t) {
    const int p = t >> 1;            // tap 0..8
    const int ch = (t & 1) << 7;     // c-half byte offset
    const int dy = p / 3 - 1, dx = p - (p / 3) * 3 - 1;
    const int offA = (p << 8) + ch;
    const int offB = ((dy * PH + dx) << 8) + ch;
    char* base = sMem + buf * 32768;
#pragma unroll
    for (int c = 0; c < 4; ++c)
      GLD_LDS16(wtc + aSrc0 + c * 18432 + offA, base + aDst + c * 1024);
#pragma unroll
    for (int c = 0; c < 4; ++c)
      GLD_LDS16(xpc + bSrc[c] + offB, base + bDst + c * 1024);
  };

  f32x4 acc[4][4] = {};

  STAGE(0, 0);
  __syncthreads();  // drains stage(0)

  for (int t = 0; t < 18; ++t) {
    const char* base = sMem + (t & 1) * 32768;
    __builtin_amdgcn_s_barrier();  // B1: reads of buf^1 (iter t-1) complete
    if (t < 17) {
      STAGE((t + 1) & 1, t + 1);
      asm volatile("s_waitcnt vmcnt(8)" ::: "memory");  // stage(t) landed
    } else {
      asm volatile("s_waitcnt vmcnt(0)" ::: "memory");
    }
    __builtin_amdgcn_s_barrier();  // B2: everyone's stage(t) landed

    f16x8 bfr[4][2];
#pragma unroll
    for (int j = 0; j < 4; ++j)
#pragma unroll
      for (int ko = 0; ko < 2; ++ko)
        bfr[j][ko] = *reinterpret_cast<const f16x8*>(base + bro[j][ko]);
#pragma unroll
    for (int i = 0; i < 4; ++i) {
      f16x8 a0 = *reinterpret_cast<const f16x8*>(base + aro[i][0]);
      f16x8 a1 = *reinterpret_cast<const f16x8*>(base + aro[i][1]);
      __builtin_amdgcn_s_setprio(1);
#pragma unroll
      for (int j = 0; j < 4; ++j) {
        acc[i][j] = __builtin_amdgcn_mfma_f32_16x16x32_f16(a0, bfr[j][0], acc[i][j], 0, 0, 0);
        acc[i][j] = __builtin_amdgcn_mfma_f32_16x16x32_f16(a1, bfr[j][1], acc[i][j], 0, 0, 0);
      }
      __builtin_amdgcn_s_setprio(0);
    }
  }

  const float sc = scale[0];
#pragma unroll
  for (int j = 0; j < 4; ++j) {
    int n = n0 + wn * 64 + j * 16 + (lane & 15);
    int b = n / HW2;
    int r = n - b * HW2;  // ho*56+wo
    float pv = po[n];
    float* op = out + (size_t)b * (COUT * HW2) + r;
#pragma unroll
    for (int i = 0; i < 4; ++i) {
      int cl = m0 + wm * 64 + i * 16 + ((lane >> 4) << 2);
      f32x4 th = *reinterpret_cast<const f32x4*>(&thresh[cl]);
#pragma unroll
      for (int q = 0; q < 4; ++q) {
        float cv = acc[i][j][q];
        float g = 1.f / (1.f + __expf(-sc * (cv - th[q])));
        op[(size_t)(cl + q) * HW2] = cv + g * pv;
      }
    }
  }
}

extern "C" void kernel_launch(void* const* d_in, const int* in_sizes, int n_in,
                              void* d_out, int out_size, void* d_ws, size_t ws_size,
                              hipStream_t stream) {
  (void)in_sizes; (void)n_in; (void)out_size; (void)ws_size;
  const float* x      = (const float*)d_in[0];
  const float* core   = (const float*)d_in[1];
  const float* per    = (const float*)d_in[2];
  const float* thresh = (const float*)d_in[3];
  const float* scale  = (const float*)d_in[4];
  float* out = (float*)d_out;

  char* ws = (char*)d_ws;
  unsigned short* xp  = (unsigned short*)ws;                  // 32*58*58*128*2 = 27,557,888 B
  unsigned short* w_t = (unsigned short*)(ws + 27557888);     // 589,824 B
  float* xs           = (float*)(ws + 28147712);              // 401,408 B
  float* po           = (float*)(ws + 28549120);              // 401,408 B

  prep_x<<<NB * HW + 456, 256, 0, stream>>>(x, xp, xs);  // +456 halo blocks
  prep_w<<<(COUT * 9 * CIN) / 256, 256, 0, stream>>>(core, w_t);
  periph_k<<<NPIX / 256, 256, 0, stream>>>(xs, per, po);
  gemm_k<<<2 * (NPIX / 128), 256, 0, stream>>>(xp, w_t, po, thresh, scale, out);
}